// Round 2
// baseline (2523.020 us; speedup 1.0000x reference)
//
#include <hip/hip_runtime.h>
#include <math.h>

// Problem dims
constexpr int B = 8;
constexpr int S = 2048;
constexpr int D = 512;
constexpr int BS = B * S;          // 16384 rows
constexpr float LN_EPS = 1e-5f;
constexpr float ATTN_SCALE = 0.04419417382415922f;  // 1/sqrt(512)

// Workspace budget notes (bytes):
//   fused/q        : BS*D*4                = 33.55 MB   (ws offset 0)
//   Slot2          : max(S*S, BS*256)*4    = 16.78 MB   (ws offset 33.55 MB)
//   attn out / t   : lives in d_out (BS*D) -- harness scratch-legal
//   peak ws        : 50.33 MB  (R1 bug: h at 67..134 MB overflowed ws -> OOB
//                    writes corrupted harness pristine copies; post-timing fail)

// ---------------------------------------------------------------------------
// Reductions (256-thread blocks = 4 waves of 64)
// ---------------------------------------------------------------------------
__device__ __forceinline__ float blk_reduce_sum(float v, float* sm) {
#pragma unroll
    for (int o = 32; o; o >>= 1) v += __shfl_down(v, o, 64);
    __syncthreads();  // protect sm reuse across calls
    if ((threadIdx.x & 63) == 0) sm[threadIdx.x >> 6] = v;
    __syncthreads();
    return sm[0] + sm[1] + sm[2] + sm[3];
}

__device__ __forceinline__ float blk_reduce_max(float v, float* sm) {
#pragma unroll
    for (int o = 32; o; o >>= 1) v = fmaxf(v, __shfl_down(v, o, 64));
    __syncthreads();
    if ((threadIdx.x & 63) == 0) sm[threadIdx.x >> 6] = v;
    __syncthreads();
    return fmaxf(fmaxf(sm[0], sm[1]), fmaxf(sm[2], sm[3]));
}

// ---------------------------------------------------------------------------
// GEMM tile config: 64x64 tile, BK=16, 256 threads, 4x4 micro-tile.
// As/Bs stored [16][68]: stride 68 -> 16B-aligned float4 rows, broken pow2.
// ---------------------------------------------------------------------------

// Kernel 1: gate = sigmoid([NX,CD] @ Wg + bg); fused = gate*NX + (1-gate)*CD
__global__ __launch_bounds__(256) void gate_fuse_gemm(
    const float* __restrict__ NX, const float* __restrict__ CD,
    const float* __restrict__ Wg, const float* __restrict__ bg,
    float* __restrict__ fused) {
    __shared__ float As[16][68];
    __shared__ float Bs[16][68];
    const int tid = threadIdx.x;
    const int tx = tid & 15, ty = tid >> 4;
    const int m0 = blockIdx.y * 64, n0 = blockIdx.x * 64;
    float acc[4][4] = {};

    for (int k0 = 0; k0 < 1024; k0 += 16) {
        {
            const int lm = tid >> 2, lk = (tid & 3) * 4;
            const float* Abase = (k0 < 512) ? NX : CD;
            const int kk = k0 & 511;
            float4 v = *(const float4*)(Abase + (size_t)(m0 + lm) * 512 + kk + lk);
            As[lk + 0][lm] = v.x; As[lk + 1][lm] = v.y;
            As[lk + 2][lm] = v.z; As[lk + 3][lm] = v.w;
        }
        {
            const int lk = tid >> 4, ln = (tid & 15) * 4;
            *(float4*)&Bs[lk][ln] = *(const float4*)(Wg + (size_t)(k0 + lk) * 512 + n0 + ln);
        }
        __syncthreads();
#pragma unroll
        for (int kk = 0; kk < 16; kk++) {
            float4 a4 = *(const float4*)&As[kk][ty * 4];
            float4 b4 = *(const float4*)&Bs[kk][tx * 4];
            float av[4] = {a4.x, a4.y, a4.z, a4.w};
            float bv[4] = {b4.x, b4.y, b4.z, b4.w};
#pragma unroll
            for (int i = 0; i < 4; i++)
#pragma unroll
                for (int j = 0; j < 4; j++)
                    acc[i][j] = fmaf(av[i], bv[j], acc[i][j]);
        }
        __syncthreads();
    }
#pragma unroll
    for (int i = 0; i < 4; i++) {
        const int m = m0 + ty * 4 + i;
#pragma unroll
        for (int j = 0; j < 4; j++) {
            const int n = n0 + tx * 4 + j;
            const float z = acc[i][j] + bg[n];
            const float g = 1.f / (1.f + expf(-z));
            const size_t idx = (size_t)m * 512 + n;
            fused[idx] = g * NX[idx] + (1.f - g) * CD[idx];
        }
    }
}

// Kernel 2: Sc = (Q @ K^T) * scale for ONE batch.  M=N=2048, K=512
__global__ __launch_bounds__(256) void scores_gemm(
    const float* __restrict__ Q, const float* __restrict__ Kx,
    float* __restrict__ Sc) {
    __shared__ float As[16][68];
    __shared__ float Bs[16][68];
    const int tid = threadIdx.x;
    const int tx = tid & 15, ty = tid >> 4;
    const int m0 = blockIdx.y * 64, n0 = blockIdx.x * 64;
    float acc[4][4] = {};

    for (int k0 = 0; k0 < 512; k0 += 16) {
        {
            const int lm = tid >> 2, lk = (tid & 3) * 4;
            float4 v = *(const float4*)(Q + (size_t)(m0 + lm) * 512 + k0 + lk);
            As[lk + 0][lm] = v.x; As[lk + 1][lm] = v.y;
            As[lk + 2][lm] = v.z; As[lk + 3][lm] = v.w;
        }
        {
            const int ln = tid >> 2, lk = (tid & 3) * 4;
            float4 v = *(const float4*)(Kx + (size_t)(n0 + ln) * 512 + k0 + lk);
            Bs[lk + 0][ln] = v.x; Bs[lk + 1][ln] = v.y;
            Bs[lk + 2][ln] = v.z; Bs[lk + 3][ln] = v.w;
        }
        __syncthreads();
#pragma unroll
        for (int kk = 0; kk < 16; kk++) {
            float4 a4 = *(const float4*)&As[kk][ty * 4];
            float4 b4 = *(const float4*)&Bs[kk][tx * 4];
            float av[4] = {a4.x, a4.y, a4.z, a4.w};
            float bv[4] = {b4.x, b4.y, b4.z, b4.w};
#pragma unroll
            for (int i = 0; i < 4; i++)
#pragma unroll
                for (int j = 0; j < 4; j++)
                    acc[i][j] = fmaf(av[i], bv[j], acc[i][j]);
        }
        __syncthreads();
    }
#pragma unroll
    for (int i = 0; i < 4; i++) {
        const int m = m0 + ty * 4 + i;
#pragma unroll
        for (int j = 0; j < 4; j++)
            Sc[(size_t)m * S + n0 + tx * 4 + j] = acc[i][j] * ATTN_SCALE;
    }
}

// Kernel 3: row softmax over 2048 elements; one block per row
__global__ __launch_bounds__(256) void softmax_rows(float* __restrict__ Sc) {
    __shared__ float sm[4];
    float* row = Sc + (size_t)blockIdx.x * 2048;
    const int t = threadIdx.x;
    float e[8];
    float mx = -1e30f;
#pragma unroll
    for (int j = 0; j < 8; j++) { e[j] = row[t + 256 * j]; mx = fmaxf(mx, e[j]); }
    mx = blk_reduce_max(mx, sm);
    float s = 0.f;
#pragma unroll
    for (int j = 0; j < 8; j++) { e[j] = expf(e[j] - mx); s += e[j]; }
    s = blk_reduce_sum(s, sm);
    const float inv = 1.f / s;
#pragma unroll
    for (int j = 0; j < 8; j++) row[t + 256 * j] = e[j] * inv;
}

// Kernel 4: O = P @ V for ONE batch.  M=2048, N=512, K=2048
__global__ __launch_bounds__(256) void pv_gemm(
    const float* __restrict__ P, const float* __restrict__ V,
    float* __restrict__ O) {
    __shared__ float As[16][68];
    __shared__ float Bs[16][68];
    const int tid = threadIdx.x;
    const int tx = tid & 15, ty = tid >> 4;
    const int m0 = blockIdx.y * 64, n0 = blockIdx.x * 64;
    float acc[4][4] = {};

    for (int k0 = 0; k0 < 2048; k0 += 16) {
        {
            const int lm = tid >> 2, lk = (tid & 3) * 4;
            float4 v = *(const float4*)(P + (size_t)(m0 + lm) * 2048 + k0 + lk);
            As[lk + 0][lm] = v.x; As[lk + 1][lm] = v.y;
            As[lk + 2][lm] = v.z; As[lk + 3][lm] = v.w;
        }
        {
            const int lk = tid >> 4, ln = (tid & 15) * 4;
            *(float4*)&Bs[lk][ln] = *(const float4*)(V + (size_t)(k0 + lk) * 512 + n0 + ln);
        }
        __syncthreads();
#pragma unroll
        for (int kk = 0; kk < 16; kk++) {
            float4 a4 = *(const float4*)&As[kk][ty * 4];
            float4 b4 = *(const float4*)&Bs[kk][tx * 4];
            float av[4] = {a4.x, a4.y, a4.z, a4.w};
            float bv[4] = {b4.x, b4.y, b4.z, b4.w};
#pragma unroll
            for (int i = 0; i < 4; i++)
#pragma unroll
                for (int j = 0; j < 4; j++)
                    acc[i][j] = fmaf(av[i], bv[j], acc[i][j]);
        }
        __syncthreads();
    }
#pragma unroll
    for (int i = 0; i < 4; i++) {
        const int m = m0 + ty * 4 + i;
#pragma unroll
        for (int j = 0; j < 4; j++)
            O[(size_t)m * 512 + n0 + tx * 4 + j] = acc[i][j];
    }
}

// Kernel 5: O = LN(AI + BI) * g + be   (O may alias AI; per-row blocks)
__global__ __launch_bounds__(256) void add_ln(
    const float* __restrict__ AI, const float* __restrict__ BI,
    const float* __restrict__ g, const float* __restrict__ be,
    float* __restrict__ O) {
    __shared__ float sm[4];
    const size_t base = (size_t)blockIdx.x * 512;
    const int t = threadIdx.x;
    const float v0 = AI[base + t] + BI[base + t];
    const float v1 = AI[base + t + 256] + BI[base + t + 256];
    const float mu = blk_reduce_sum(v0 + v1, sm) * (1.f / 512.f);
    const float d0 = v0 - mu, d1 = v1 - mu;
    const float var = blk_reduce_sum(d0 * d0 + d1 * d1, sm) * (1.f / 512.f);
    const float rs = rsqrtf(var + LN_EPS);
    O[base + t] = d0 * rs * g[t] + be[t];
    O[base + t + 256] = d1 * rs * g[t + 256] + be[t + 256];
}

// Kernel 6: O = LN(T) * g + be  (O may alias T; per-row in-place safe)
__global__ __launch_bounds__(256) void ln_only(
    const float* __restrict__ T, const float* __restrict__ g,
    const float* __restrict__ be, float* __restrict__ O) {
    __shared__ float sm[4];
    const size_t base = (size_t)blockIdx.x * 512;
    const int t = threadIdx.x;
    const float v0 = T[base + t];
    const float v1 = T[base + t + 256];
    const float mu = blk_reduce_sum(v0 + v1, sm) * (1.f / 512.f);
    const float d0 = v0 - mu, d1 = v1 - mu;
    const float var = blk_reduce_sum(d0 * d0 + d1 * d1, sm) * (1.f / 512.f);
    const float rs = rsqrtf(var + LN_EPS);
    O[base + t] = d0 * rs * g[t] + be[t];
    O[base + t + 256] = d1 * rs * g[t + 256] + be[t + 256];
}

// Kernel 7: H = gelu(Q @ W1[:, nb..nb+256) + b1[nb..])  H is [BS x 256]
__global__ __launch_bounds__(256) void ffn1_part(
    const float* __restrict__ Q, const float* __restrict__ W1,
    const float* __restrict__ b1, float* __restrict__ H, int n_base) {
    __shared__ float As[16][68];
    __shared__ float Bs[16][68];
    const int tid = threadIdx.x;
    const int tx = tid & 15, ty = tid >> 4;
    const int m0 = blockIdx.y * 64, n0 = blockIdx.x * 64;
    float acc[4][4] = {};

    for (int k0 = 0; k0 < 512; k0 += 16) {
        {
            const int lm = tid >> 2, lk = (tid & 3) * 4;
            float4 v = *(const float4*)(Q + (size_t)(m0 + lm) * 512 + k0 + lk);
            As[lk + 0][lm] = v.x; As[lk + 1][lm] = v.y;
            As[lk + 2][lm] = v.z; As[lk + 3][lm] = v.w;
        }
        {
            const int lk = tid >> 4, ln = (tid & 15) * 4;
            *(float4*)&Bs[lk][ln] =
                *(const float4*)(W1 + (size_t)(k0 + lk) * 1024 + n_base + n0 + ln);
        }
        __syncthreads();
#pragma unroll
        for (int kk = 0; kk < 16; kk++) {
            float4 a4 = *(const float4*)&As[kk][ty * 4];
            float4 b4 = *(const float4*)&Bs[kk][tx * 4];
            float av[4] = {a4.x, a4.y, a4.z, a4.w};
            float bv[4] = {b4.x, b4.y, b4.z, b4.w};
#pragma unroll
            for (int i = 0; i < 4; i++)
#pragma unroll
                for (int j = 0; j < 4; j++)
                    acc[i][j] = fmaf(av[i], bv[j], acc[i][j]);
        }
        __syncthreads();
    }
#pragma unroll
    for (int i = 0; i < 4; i++) {
        const int m = m0 + ty * 4 + i;
#pragma unroll
        for (int j = 0; j < 4; j++) {
            const int n = n0 + tx * 4 + j;               // within [0,256)
            const float x = acc[i][j] + b1[n_base + n];
            H[(size_t)m * 256 + n] = 0.5f * x * (1.f + erff(x * 0.70710678118654752f));
        }
    }
}

// Kernel 8: T (+)= H @ W2[kb..kb+256, :]; init pass adds Q + b2.
// H is [BS x 256]; T is [BS x 512]
__global__ __launch_bounds__(256) void ffn2_part(
    const float* __restrict__ H, const float* __restrict__ W2,
    const float* __restrict__ b2, const float* __restrict__ Q,
    float* __restrict__ T, int k_base, int init) {
    __shared__ float As[16][68];
    __shared__ float Bs[16][68];
    const int tid = threadIdx.x;
    const int tx = tid & 15, ty = tid >> 4;
    const int m0 = blockIdx.y * 64, n0 = blockIdx.x * 64;
    float acc[4][4] = {};

    for (int k0 = 0; k0 < 256; k0 += 16) {
        {
            const int lm = tid >> 2, lk = (tid & 3) * 4;
            float4 v = *(const float4*)(H + (size_t)(m0 + lm) * 256 + k0 + lk);
            As[lk + 0][lm] = v.x; As[lk + 1][lm] = v.y;
            As[lk + 2][lm] = v.z; As[lk + 3][lm] = v.w;
        }
        {
            const int lk = tid >> 4, ln = (tid & 15) * 4;
            *(float4*)&Bs[lk][ln] =
                *(const float4*)(W2 + (size_t)(k_base + k0 + lk) * 512 + n0 + ln);
        }
        __syncthreads();
#pragma unroll
        for (int kk = 0; kk < 16; kk++) {
            float4 a4 = *(const float4*)&As[kk][ty * 4];
            float4 b4 = *(const float4*)&Bs[kk][tx * 4];
            float av[4] = {a4.x, a4.y, a4.z, a4.w};
            float bv[4] = {b4.x, b4.y, b4.z, b4.w};
#pragma unroll
            for (int i = 0; i < 4; i++)
#pragma unroll
                for (int j = 0; j < 4; j++)
                    acc[i][j] = fmaf(av[i], bv[j], acc[i][j]);
        }
        __syncthreads();
    }
#pragma unroll
    for (int i = 0; i < 4; i++) {
        const int m = m0 + ty * 4 + i;
#pragma unroll
        for (int j = 0; j < 4; j++) {
            const int n = n0 + tx * 4 + j;
            const size_t idx = (size_t)m * 512 + n;
            if (init) T[idx] = acc[i][j] + b2[n] + Q[idx];
            else      T[idx] += acc[i][j];
        }
    }
}

// ---------------------------------------------------------------------------
extern "C" void kernel_launch(void* const* d_in, const int* in_sizes, int n_in,
                              void* d_out, int out_size, void* d_ws, size_t ws_size,
                              hipStream_t stream) {
    const float* NX  = (const float*)d_in[0];
    const float* X   = (const float*)d_in[1];
    const float* CD  = (const float*)d_in[2];
    const float* Wg  = (const float*)d_in[3];
    const float* bg  = (const float*)d_in[4];
    const float* W1  = (const float*)d_in[5];
    const float* b1  = (const float*)d_in[6];
    const float* W2  = (const float*)d_in[7];
    const float* b2  = (const float*)d_in[8];
    const float* g1  = (const float*)d_in[9];
    const float* be1 = (const float*)d_in[10];
    const float* g2  = (const float*)d_in[11];
    const float* be2 = (const float*)d_in[12];
    float* out = (float*)d_out;

    float* ws    = (float*)d_ws;
    float* fused = ws;                        // BS*D floats (later holds q)
    float* slot2 = ws + (size_t)BS * D;       // max(S*S, BS*256) floats

    // 1) gated fusion -> fused
    gate_fuse_gemm<<<dim3(D / 64, BS / 64), 256, 0, stream>>>(NX, CD, Wg, bg, fused);

    // 2) attention per batch: scores in slot2 (S*S), attn output into d_out
    for (int b = 0; b < B; b++) {
        const size_t ob = (size_t)b * S * D;
        scores_gemm<<<dim3(S / 64, S / 64), 256, 0, stream>>>(fused + ob, X + ob, slot2);
        softmax_rows<<<S, 256, 0, stream>>>(slot2);
        pv_gemm<<<dim3(D / 64, S / 64), 256, 0, stream>>>(slot2, X + ob, out + ob);
    }

    // 3) q = LN(fused + attn) -> fused (in place); d_out free after this
    add_ln<<<BS, 256, 0, stream>>>(fused, out, g1, be1, fused);

    // 4+5) FFN in 4 column/row-block passes; hidden quarter in slot2 (BS*256),
    //      t accumulates in d_out
    for (int p = 0; p < 4; p++) {
        ffn1_part<<<dim3(4, BS / 64), 256, 0, stream>>>(fused, W1, b1, slot2, p * 256);
        ffn2_part<<<dim3(8, BS / 64), 256, 0, stream>>>(slot2, W2, b2, fused, out,
                                                        p * 256, p == 0 ? 1 : 0);
    }

    // 6) out = LN(t) in place
    ln_only<<<BS, 256, 0, stream>>>(out, g2, be2, out);
}

// Round 3
// 656.860 us; speedup vs baseline: 3.8410x; 3.8410x over previous
//
#include <hip/hip_runtime.h>
#include <math.h>

typedef unsigned short ushort_t;
typedef unsigned int uint_t;
typedef __attribute__((ext_vector_type(8))) short short8;
typedef __attribute__((ext_vector_type(4))) float floatx4;

// Problem dims
constexpr int B = 8;
constexpr int S = 2048;
constexpr int D = 512;
constexpr int BS = B * S;          // 16384 rows
constexpr float LN_EPS = 1e-5f;
constexpr float ATTN_SCALE = 0.04419417382415922f;  // 1/sqrt(512)

// ---------------------------------------------------------------------------
// bf16 helpers (RNE)
// ---------------------------------------------------------------------------
__device__ __forceinline__ ushort_t f2bf(float f) {
    union { float f; uint_t u; } x; x.f = f;
    uint_t r = x.u + 0x7fffu + ((x.u >> 16) & 1u);
    return (ushort_t)(r >> 16);
}
__device__ __forceinline__ float bf2f(ushort_t h) {
    union { uint_t u; float f; } y; y.u = ((uint_t)h) << 16;
    return y.f;
}

// ---------------------------------------------------------------------------
// Reductions (256-thread blocks = 4 waves of 64)
// ---------------------------------------------------------------------------
__device__ __forceinline__ float blk_reduce_sum(float v, float* sm) {
#pragma unroll
    for (int o = 32; o; o >>= 1) v += __shfl_down(v, o, 64);
    __syncthreads();
    if ((threadIdx.x & 63) == 0) sm[threadIdx.x >> 6] = v;
    __syncthreads();
    return sm[0] + sm[1] + sm[2] + sm[3];
}
__device__ __forceinline__ float blk_reduce_max(float v, float* sm) {
#pragma unroll
    for (int o = 32; o; o >>= 1) v = fmaxf(v, __shfl_down(v, o, 64));
    __syncthreads();
    if ((threadIdx.x & 63) == 0) sm[threadIdx.x >> 6] = v;
    __syncthreads();
    return fmaxf(fmaxf(sm[0], sm[1]), fmaxf(sm[2], sm[3]));
}

// ---------------------------------------------------------------------------
// Conversions
// ---------------------------------------------------------------------------
// fp32 -> bf16 elementwise, 8 elems/thread
__global__ __launch_bounds__(256) void conv_bf16(
    const float* __restrict__ in, ushort_t* __restrict__ out) {
    const size_t i8 = ((size_t)blockIdx.x * 256 + threadIdx.x) * 8;
    float4 f0 = *(const float4*)(in + i8);
    float4 f1 = *(const float4*)(in + i8 + 4);
    short8 pk;
    pk[0] = (short)f2bf(f0.x); pk[1] = (short)f2bf(f0.y);
    pk[2] = (short)f2bf(f0.z); pk[3] = (short)f2bf(f0.w);
    pk[4] = (short)f2bf(f1.x); pk[5] = (short)f2bf(f1.y);
    pk[6] = (short)f2bf(f1.z); pk[7] = (short)f2bf(f1.w);
    *(short8*)(out + i8) = pk;
}

// fp32 [R][C] -> bf16 [C][R] (transpose + convert), 32x32 tiles, 256 threads
__global__ __launch_bounds__(256) void transpose_cvt(
    const float* __restrict__ in, ushort_t* __restrict__ out, int R, int C) {
    __shared__ float tl[32][33];
    const int tx = threadIdx.x & 31, ty = threadIdx.x >> 5;  // ty 0..7
    const int c0 = blockIdx.x * 32, r0 = blockIdx.y * 32;
#pragma unroll
    for (int i = 0; i < 4; i++)
        tl[ty + i * 8][tx] = in[(size_t)(r0 + ty + i * 8) * C + c0 + tx];
    __syncthreads();
#pragma unroll
    for (int i = 0; i < 4; i++)
        out[(size_t)(c0 + ty + i * 8) * R + r0 + tx] = f2bf(tl[tx][ty + i * 8]);
}

// ---------------------------------------------------------------------------
// MFMA GEMM core: C[M,N] = A[M,K] * Bt[N,K]^T ; 128x128 tile, BK=32, 256 thr.
// LDS rows stride 40 bf16 (80B, 16B-aligned, conflict-light).
// Wave w -> 64x64 quadrant; 4x4 grid of 16x16x32 mfma. acc = 64 VGPR.
// ---------------------------------------------------------------------------
#define GEMM_PREAMBLE()                                                        \
    __shared__ ushort_t As[128 * 40];                                          \
    __shared__ ushort_t Bs[128 * 40];                                          \
    const int t = threadIdx.x;                                                 \
    const int m0 = blockIdx.y * 128, n0 = blockIdx.x * 128;                    \
    const int sr = t >> 2;               /* 0..63 */                           \
    const int sc = (t & 3) * 8;          /* 0,8,16,24 */                       \
    const int lane = t & 63, w = t >> 6;                                       \
    const int wm = (w >> 1) * 64, wn = (w & 1) * 64;                           \
    const int fr = lane & 15, fq = lane >> 4;                                  \
    floatx4 acc[4][4];                                                         \
    _Pragma("unroll") for (int i = 0; i < 4; i++)                              \
        _Pragma("unroll") for (int j = 0; j < 4; j++) {                        \
            acc[i][j][0] = 0.f; acc[i][j][1] = 0.f;                            \
            acc[i][j][2] = 0.f; acc[i][j][3] = 0.f; }

#define GEMM_MFMA_STAGE()                                                      \
    short8 af[4], bfg[4];                                                      \
    _Pragma("unroll") for (int i = 0; i < 4; i++) {                            \
        af[i]  = *(const short8*)&As[(wm + i * 16 + fr) * 40 + fq * 8];        \
        bfg[i] = *(const short8*)&Bs[(wn + i * 16 + fr) * 40 + fq * 8];        \
    }                                                                          \
    _Pragma("unroll") for (int i = 0; i < 4; i++)                              \
        _Pragma("unroll") for (int j = 0; j < 4; j++)                          \
            acc[i][j] = __builtin_amdgcn_mfma_f32_16x16x32_bf16(               \
                af[i], bfg[j], acc[i][j], 0, 0, 0);

// EPI: 0 = scale + bf16 store; 1 = +bias, exact gelu, bf16 store;
//      2 = fp32 accumulate in place (T[idx] += acc [+ bias if init])
template <int EPI>
__global__ __launch_bounds__(256) void gemm_std(
    const ushort_t* __restrict__ A, int lda, long sAz,
    const ushort_t* __restrict__ Bt, int ldb, long sBz,
    void* __restrict__ Cv, int ldc, long sCz,
    int K, const float* __restrict__ bias, float scale, int init) {
    GEMM_PREAMBLE();
    const ushort_t* Ab = A + (size_t)blockIdx.z * sAz + (size_t)m0 * lda;
    const ushort_t* Bb = Bt + (size_t)blockIdx.z * sBz + (size_t)n0 * ldb;

    for (int k0 = 0; k0 < K; k0 += 32) {
        int4 a0 = *(const int4*)(Ab + (size_t)sr * lda + k0 + sc);
        int4 a1 = *(const int4*)(Ab + (size_t)(sr + 64) * lda + k0 + sc);
        int4 b0 = *(const int4*)(Bb + (size_t)sr * ldb + k0 + sc);
        int4 b1 = *(const int4*)(Bb + (size_t)(sr + 64) * ldb + k0 + sc);
        __syncthreads();
        *(int4*)&As[sr * 40 + sc] = a0;
        *(int4*)&As[(sr + 64) * 40 + sc] = a1;
        *(int4*)&Bs[sr * 40 + sc] = b0;
        *(int4*)&Bs[(sr + 64) * 40 + sc] = b1;
        __syncthreads();
        GEMM_MFMA_STAGE();
    }

#pragma unroll
    for (int i = 0; i < 4; i++) {
#pragma unroll
        for (int j = 0; j < 4; j++) {
#pragma unroll
            for (int r = 0; r < 4; r++) {
                const int m = m0 + wm + i * 16 + fq * 4 + r;
                const int n = n0 + wn + j * 16 + fr;
                float v = acc[i][j][r];
                if (EPI == 0) {
                    ushort_t* C = (ushort_t*)Cv + (size_t)blockIdx.z * sCz;
                    C[(size_t)m * ldc + n] = f2bf(v * scale);
                } else if (EPI == 1) {
                    const float x = v + bias[n];
                    const float gl = 0.5f * x * (1.f + erff(x * 0.70710678118654752f));
                    ushort_t* C = (ushort_t*)Cv;
                    C[(size_t)m * ldc + n] = f2bf(gl);
                } else {
                    float* T = (float*)Cv;
                    const size_t idx = (size_t)m * ldc + n;
                    T[idx] = T[idx] + v + (init ? bias[n] : 0.f);
                }
            }
        }
    }
}

// Gate GEMM: A = concat(NX,CD) fp32 (convert in staging), B = WgT bf16 [512][1024]
// Epilogue: g = sigmoid(acc + bg); Fb = bf16(g*NX + (1-g)*CD).  M=BS,N=512,K=1024
__global__ __launch_bounds__(256) void gate_gemm(
    const float* __restrict__ NX, const float* __restrict__ CD,
    const ushort_t* __restrict__ WgT, const float* __restrict__ bg,
    ushort_t* __restrict__ Fb) {
    GEMM_PREAMBLE();
    const ushort_t* Bb = WgT + (size_t)n0 * 1024;

    for (int k0 = 0; k0 < 1024; k0 += 32) {
        const float* Asrc = (k0 < 512) ? NX : CD;
        const int kk = k0 & 511;
        const float* p0 = Asrc + (size_t)(m0 + sr) * 512 + kk + sc;
        const float* p1 = Asrc + (size_t)(m0 + sr + 64) * 512 + kk + sc;
        float4 f00 = *(const float4*)p0;       float4 f01 = *(const float4*)(p0 + 4);
        float4 f10 = *(const float4*)p1;       float4 f11 = *(const float4*)(p1 + 4);
        int4 b0 = *(const int4*)(Bb + (size_t)sr * 1024 + k0 + sc);
        int4 b1 = *(const int4*)(Bb + (size_t)(sr + 64) * 1024 + k0 + sc);
        short8 pa0, pa1;
        pa0[0] = (short)f2bf(f00.x); pa0[1] = (short)f2bf(f00.y);
        pa0[2] = (short)f2bf(f00.z); pa0[3] = (short)f2bf(f00.w);
        pa0[4] = (short)f2bf(f01.x); pa0[5] = (short)f2bf(f01.y);
        pa0[6] = (short)f2bf(f01.z); pa0[7] = (short)f2bf(f01.w);
        pa1[0] = (short)f2bf(f10.x); pa1[1] = (short)f2bf(f10.y);
        pa1[2] = (short)f2bf(f10.z); pa1[3] = (short)f2bf(f10.w);
        pa1[4] = (short)f2bf(f11.x); pa1[5] = (short)f2bf(f11.y);
        pa1[6] = (short)f2bf(f11.z); pa1[7] = (short)f2bf(f11.w);
        __syncthreads();
        *(short8*)&As[sr * 40 + sc] = pa0;
        *(short8*)&As[(sr + 64) * 40 + sc] = pa1;
        *(int4*)&Bs[sr * 40 + sc] = b0;
        *(int4*)&Bs[(sr + 64) * 40 + sc] = b1;
        __syncthreads();
        GEMM_MFMA_STAGE();
    }

#pragma unroll
    for (int i = 0; i < 4; i++) {
#pragma unroll
        for (int j = 0; j < 4; j++) {
#pragma unroll
            for (int r = 0; r < 4; r++) {
                const int m = m0 + wm + i * 16 + fq * 4 + r;
                const int n = n0 + wn + j * 16 + fr;
                const float z = acc[i][j][r] + bg[n];
                const float g = 1.f / (1.f + expf(-z));
                const size_t idx = (size_t)m * 512 + n;
                Fb[idx] = f2bf(g * NX[idx] + (1.f - g) * CD[idx]);
            }
        }
    }
}

// PV GEMM: O[b] = P[b] @ X[b].  A = P bf16 [2048][2048]; B = Xb rows (k=seq) ->
// in-staging transpose to Bt layout (b16 scatter writes; known conflict cost).
// M=2048, N=512, K=2048, z = batch within group of 4.
__global__ __launch_bounds__(256) void pv_gemm(
    const ushort_t* __restrict__ P, const ushort_t* __restrict__ Xb,
    ushort_t* __restrict__ O) {
    GEMM_PREAMBLE();
    const ushort_t* Ab = P + (size_t)blockIdx.z * S * S + (size_t)m0 * S;
    const ushort_t* Xbb = Xb + (size_t)blockIdx.z * S * 512;
    ushort_t* Ob = O + (size_t)blockIdx.z * S * 512;

    // B transpose staging map: g = t + 256*j (j=0,1): kk = g>>4 (0..31),
    // nb = g&15; read 8 bf16 of X row (n-contig), write 8 b16 down column kk.
    const int kkA = t >> 4;          // 0..15, +16 for j=1
    const int nbA = t & 15;

    for (int k0 = 0; k0 < S; k0 += 32) {
        int4 a0 = *(const int4*)(Ab + (size_t)sr * S + k0 + sc);
        int4 a1 = *(const int4*)(Ab + (size_t)(sr + 64) * S + k0 + sc);
        int4 x0 = *(const int4*)(Xbb + (size_t)(k0 + kkA) * 512 + n0 + nbA * 8);
        int4 x1 = *(const int4*)(Xbb + (size_t)(k0 + kkA + 16) * 512 + n0 + nbA * 8);
        __syncthreads();
        *(int4*)&As[sr * 40 + sc] = a0;
        *(int4*)&As[(sr + 64) * 40 + sc] = a1;
        {
            ushort_t tmp[8];
            *(int4*)tmp = x0;
#pragma unroll
            for (int i = 0; i < 8; i++) Bs[(nbA * 8 + i) * 40 + kkA] = tmp[i];
            *(int4*)tmp = x1;
#pragma unroll
            for (int i = 0; i < 8; i++) Bs[(nbA * 8 + i) * 40 + kkA + 16] = tmp[i];
        }
        __syncthreads();
        GEMM_MFMA_STAGE();
    }

#pragma unroll
    for (int i = 0; i < 4; i++) {
#pragma unroll
        for (int j = 0; j < 4; j++) {
#pragma unroll
            for (int r = 0; r < 4; r++) {
                const int m = m0 + wm + i * 16 + fq * 4 + r;
                const int n = n0 + wn + j * 16 + fr;
                Ob[(size_t)m * 512 + n] = f2bf(acc[i][j][r]);
            }
        }
    }
}

// ---------------------------------------------------------------------------
// Softmax over bf16 rows of 2048, in place
// ---------------------------------------------------------------------------
__global__ __launch_bounds__(256) void softmax_bf16(ushort_t* __restrict__ Sc) {
    __shared__ float sm[4];
    ushort_t* row = Sc + (size_t)blockIdx.x * 2048;
    const int t = threadIdx.x;
    ushort_t raw[8];
    *(int4*)raw = *(const int4*)(row + t * 8);
    float e[8];
    float mx = -1e30f;
#pragma unroll
    for (int j = 0; j < 8; j++) { e[j] = bf2f(raw[j]); mx = fmaxf(mx, e[j]); }
    mx = blk_reduce_max(mx, sm);
    float s = 0.f;
#pragma unroll
    for (int j = 0; j < 8; j++) { e[j] = expf(e[j] - mx); s += e[j]; }
    s = blk_reduce_sum(s, sm);
    const float inv = 1.f / s;
#pragma unroll
    for (int j = 0; j < 8; j++) raw[j] = f2bf(e[j] * inv);
    *(int4*)(row + t * 8) = *(const int4*)raw;
}

// ---------------------------------------------------------------------------
// LN1: q = LN(fused + attn) -> qf (fp32, d_out) and qb (bf16)
// ---------------------------------------------------------------------------
__global__ __launch_bounds__(256) void ln1_kernel(
    const ushort_t* __restrict__ Fb, const ushort_t* __restrict__ Ab,
    const float* __restrict__ g1, const float* __restrict__ be1,
    float* __restrict__ qf, ushort_t* __restrict__ qb) {
    __shared__ float sm[4];
    const size_t base = (size_t)blockIdx.x * 512;
    const int t = threadIdx.x;
    const float v0 = bf2f(Fb[base + t]) + bf2f(Ab[base + t]);
    const float v1 = bf2f(Fb[base + t + 256]) + bf2f(Ab[base + t + 256]);
    const float mu = blk_reduce_sum(v0 + v1, sm) * (1.f / 512.f);
    const float d0 = v0 - mu, d1 = v1 - mu;
    const float var = blk_reduce_sum(d0 * d0 + d1 * d1, sm) * (1.f / 512.f);
    const float rs = rsqrtf(var + LN_EPS);
    const float y0 = d0 * rs * g1[t] + be1[t];
    const float y1 = d1 * rs * g1[t + 256] + be1[t + 256];
    qf[base + t] = y0;          qf[base + t + 256] = y1;
    qb[base + t] = f2bf(y0);    qb[base + t + 256] = f2bf(y1);
}

// Final LN in place on fp32
__global__ __launch_bounds__(256) void ln2_kernel(
    float* __restrict__ T, const float* __restrict__ g,
    const float* __restrict__ be) {
    __shared__ float sm[4];
    const size_t base = (size_t)blockIdx.x * 512;
    const int t = threadIdx.x;
    const float v0 = T[base + t];
    const float v1 = T[base + t + 256];
    const float mu = blk_reduce_sum(v0 + v1, sm) * (1.f / 512.f);
    const float d0 = v0 - mu, d1 = v1 - mu;
    const float var = blk_reduce_sum(d0 * d0 + d1 * d1, sm) * (1.f / 512.f);
    const float rs = rsqrtf(var + LN_EPS);
    T[base + t] = d0 * rs * g[t] + be[t];
    T[base + t + 256] = d1 * rs * g[t + 256] + be[t + 256];
}

// ---------------------------------------------------------------------------
extern "C" void kernel_launch(void* const* d_in, const int* in_sizes, int n_in,
                              void* d_out, int out_size, void* d_ws, size_t ws_size,
                              hipStream_t stream) {
    const float* NX  = (const float*)d_in[0];
    const float* X   = (const float*)d_in[1];
    const float* CD  = (const float*)d_in[2];
    const float* Wg  = (const float*)d_in[3];
    const float* bg  = (const float*)d_in[4];
    const float* W1  = (const float*)d_in[5];
    const float* b1  = (const float*)d_in[6];
    const float* W2  = (const float*)d_in[7];
    const float* b2  = (const float*)d_in[8];
    const float* g1  = (const float*)d_in[9];
    const float* be1 = (const float*)d_in[10];
    const float* g2  = (const float*)d_in[11];
    const float* be2 = (const float*)d_in[12];

    // ws layout (total exactly 50,331,648 B = R2's proven-safe size):
    ushort_t* Xb  = (ushort_t*)d_ws;                          // [BS*512] bf16
    ushort_t* Fb  = (ushort_t*)((char*)d_ws + 16777216);      // [BS*512] bf16
    ushort_t* R2  = (ushort_t*)((char*)d_ws + 33554432);      // 16.78 MB multi-use
    ushort_t* WgT = R2;                                       // [512][1024] (gate)
    ushort_t* attnb = R2;                                     // [BS*512] (attention)
    ushort_t* hbuf  = R2;                                     // [BS*512] (FFN half)
    ushort_t* qb  = Xb;                                       // after attention
    ushort_t* W1T = Fb;                                       // [1024][512] after LN1
    ushort_t* W2T = Fb + 524288;                              // [512][1024]
    ushort_t* Scb = (ushort_t*)d_out;                         // 4 batches of [S][S] bf16
    float*    qf  = (float*)d_out;

    // 1) conversions
    conv_bf16<<<BS * 512 / 2048, 256, 0, stream>>>(X, Xb);
    transpose_cvt<<<dim3(512 / 32, 1024 / 32), 256, 0, stream>>>(Wg, WgT, 1024, 512);

    // 2) gated fusion -> Fb (bf16)
    gate_gemm<<<dim3(4, 128), 256, 0, stream>>>(NX, CD, WgT, bg, Fb);

    // 3) attention in 2 groups of 4 batches; scores live in d_out as bf16
    for (int g = 0; g < 2; g++) {
        const size_t go = (size_t)g * 4 * S * 512;
        gemm_std<0><<<dim3(16, 16, 4), 256, 0, stream>>>(
            Fb + go, 512, (long)S * 512, Xb + go, 512, (long)S * 512,
            (void*)Scb, S, (long)S * S, 512, nullptr, ATTN_SCALE, 0);
        softmax_bf16<<<4 * S, 256, 0, stream>>>(Scb);
        pv_gemm<<<dim3(4, 16, 4), 256, 0, stream>>>(Scb, Xb + go, attnb + go);
    }

    // 4) q = LN(fused + attn): qf -> d_out (scores dead), qb -> ws0 (Xb dead)
    ln1_kernel<<<BS, 256, 0, stream>>>(Fb, attnb, g1, be1, qf, qb);

    // 5) weight conversions into Fb region (Fb dead after LN1)
    transpose_cvt<<<dim3(1024 / 32, 512 / 32), 256, 0, stream>>>(W1, W1T, 512, 1024);
    transpose_cvt<<<dim3(512 / 32, 1024 / 32), 256, 0, stream>>>(W2, W2T, 1024, 512);

    // 6) FFN in 2 halves; h half in R2 (attnb dead); t accumulates in d_out
    for (int h = 0; h < 2; h++) {
        gemm_std<1><<<dim3(4, 128), 256, 0, stream>>>(
            qb, 512, 0, W1T + (size_t)h * 512 * 512, 512, 0,
            (void*)hbuf, 512, 0, 512, b1 + h * 512, 1.f, 0);
        gemm_std<2><<<dim3(4, 128), 256, 0, stream>>>(
            hbuf, 512, 0, W2T + h * 512, 1024, 0,
            (void*)qf, 512, 0, 512, b2, 1.f, h == 0 ? 1 : 0);
    }

    // 7) out = LN(t) in place in d_out
    ln2_kernel<<<BS, 256, 0, stream>>>(qf, g2, be2);
}

// Round 4
// 562.627 us; speedup vs baseline: 4.4844x; 1.1675x over previous
//
#include <hip/hip_runtime.h>
#include <math.h>

typedef unsigned short ushort_t;
typedef unsigned int uint_t;
typedef __attribute__((ext_vector_type(8))) short short8;
typedef __attribute__((ext_vector_type(4))) float floatx4;

// Problem dims
constexpr int B = 8;
constexpr int S = 2048;
constexpr int D = 512;
constexpr int BS = B * S;          // 16384 rows
constexpr float LN_EPS = 1e-5f;
constexpr float ATTN_SCALE = 0.04419417382415922f;  // 1/sqrt(512)

// ---------------------------------------------------------------------------
// bf16 helpers (RNE)
// ---------------------------------------------------------------------------
__device__ __forceinline__ ushort_t f2bf(float f) {
    union { float f; uint_t u; } x; x.f = f;
    uint_t r = x.u + 0x7fffu + ((x.u >> 16) & 1u);
    return (ushort_t)(r >> 16);
}
__device__ __forceinline__ float bf2f(ushort_t h) {
    union { uint_t u; float f; } y; y.u = ((uint_t)h) << 16;
    return y.f;
}
__device__ __forceinline__ short8 pack8(float4 a, float4 b) {
    short8 p;
    p[0] = (short)f2bf(a.x); p[1] = (short)f2bf(a.y);
    p[2] = (short)f2bf(a.z); p[3] = (short)f2bf(a.w);
    p[4] = (short)f2bf(b.x); p[5] = (short)f2bf(b.y);
    p[6] = (short)f2bf(b.z); p[7] = (short)f2bf(b.w);
    return p;
}

// ---------------------------------------------------------------------------
// Reductions (256-thread blocks = 4 waves of 64)
// ---------------------------------------------------------------------------
__device__ __forceinline__ float blk_reduce_sum(float v, float* sm) {
#pragma unroll
    for (int o = 32; o; o >>= 1) v += __shfl_down(v, o, 64);
    __syncthreads();
    if ((threadIdx.x & 63) == 0) sm[threadIdx.x >> 6] = v;
    __syncthreads();
    return sm[0] + sm[1] + sm[2] + sm[3];
}
__device__ __forceinline__ float blk_reduce_max(float v, float* sm) {
#pragma unroll
    for (int o = 32; o; o >>= 1) v = fmaxf(v, __shfl_down(v, o, 64));
    __syncthreads();
    if ((threadIdx.x & 63) == 0) sm[threadIdx.x >> 6] = v;
    __syncthreads();
    return fmaxf(fmaxf(sm[0], sm[1]), fmaxf(sm[2], sm[3]));
}

// ---------------------------------------------------------------------------
// fp32 [R][C] -> bf16 [C][R] transpose+convert; batched via blockIdx.z (z*R*C)
// ---------------------------------------------------------------------------
__global__ __launch_bounds__(256) void transpose_cvt(
    const float* __restrict__ in, ushort_t* __restrict__ out, int R, int C) {
    __shared__ float tl[32][33];
    const size_t zoff = (size_t)blockIdx.z * R * C;
    const int tx = threadIdx.x & 31, ty = threadIdx.x >> 5;  // ty 0..7
    const int c0 = blockIdx.x * 32, r0 = blockIdx.y * 32;
#pragma unroll
    for (int i = 0; i < 4; i++)
        tl[ty + i * 8][tx] = in[zoff + (size_t)(r0 + ty + i * 8) * C + c0 + tx];
    __syncthreads();
#pragma unroll
    for (int i = 0; i < 4; i++)
        out[zoff + (size_t)(c0 + ty + i * 8) * R + r0 + tx] = f2bf(tl[tx][ty + i * 8]);
}

// ---------------------------------------------------------------------------
// MFMA GEMM core: C[M,N] = A[M,K] * Bt[N,K]^T ; 128x128 tile, BK=32, 256 thr.
// LDS rows stride 40 bf16 (80B, 16B-aligned, conflict-light).
// Wave w -> 64x64 quadrant; 4x4 grid of 16x16x32 mfma.
// ---------------------------------------------------------------------------
#define GEMM_PREAMBLE()                                                        \
    __shared__ ushort_t As[128 * 40];                                          \
    __shared__ ushort_t Bs[128 * 40];                                          \
    const int t = threadIdx.x;                                                 \
    const int m0 = blockIdx.y * 128, n0 = blockIdx.x * 128;                    \
    const int sr = t >> 2;               /* 0..63 */                           \
    const int sc = (t & 3) * 8;          /* 0,8,16,24 */                       \
    const int lane = t & 63, w = t >> 6;                                       \
    const int wm = (w >> 1) * 64, wn = (w & 1) * 64;                           \
    const int fr = lane & 15, fq = lane >> 4;                                  \
    floatx4 acc[4][4];                                                         \
    _Pragma("unroll") for (int i = 0; i < 4; i++)                              \
        _Pragma("unroll") for (int j = 0; j < 4; j++) {                        \
            acc[i][j][0] = 0.f; acc[i][j][1] = 0.f;                            \
            acc[i][j][2] = 0.f; acc[i][j][3] = 0.f; }

#define GEMM_MFMA_STAGE()                                                      \
    short8 af[4], bfg[4];                                                      \
    _Pragma("unroll") for (int i = 0; i < 4; i++) {                            \
        af[i]  = *(const short8*)&As[(wm + i * 16 + fr) * 40 + fq * 8];        \
        bfg[i] = *(const short8*)&Bs[(wn + i * 16 + fr) * 40 + fq * 8];        \
    }                                                                          \
    _Pragma("unroll") for (int i = 0; i < 4; i++)                              \
        _Pragma("unroll") for (int j = 0; j < 4; j++)                          \
            acc[i][j] = __builtin_amdgcn_mfma_f32_16x16x32_bf16(               \
                af[i], bfg[j], acc[i][j], 0, 0, 0);

// EPI: 0 = scale + bf16 store; 1 = +bias, exact gelu, bf16 store;
//      2 = fp32 accumulate in place (T[idx] += acc [+ bias + keep if init])
template <int EPI>
__global__ __launch_bounds__(256) void gemm_std(
    const ushort_t* __restrict__ A, int lda, long sAz,
    const ushort_t* __restrict__ Bt, int ldb, long sBz,
    void* __restrict__ Cv, int ldc, long sCz,
    int K, const float* __restrict__ bias, float scale, int init) {
    GEMM_PREAMBLE();
    const ushort_t* Ab = A + (size_t)blockIdx.z * sAz + (size_t)m0 * lda;
    const ushort_t* Bb = Bt + (size_t)blockIdx.z * sBz + (size_t)n0 * ldb;

    for (int k0 = 0; k0 < K; k0 += 32) {
        int4 a0 = *(const int4*)(Ab + (size_t)sr * lda + k0 + sc);
        int4 a1 = *(const int4*)(Ab + (size_t)(sr + 64) * lda + k0 + sc);
        int4 b0 = *(const int4*)(Bb + (size_t)sr * ldb + k0 + sc);
        int4 b1 = *(const int4*)(Bb + (size_t)(sr + 64) * ldb + k0 + sc);
        __syncthreads();
        *(int4*)&As[sr * 40 + sc] = a0;
        *(int4*)&As[(sr + 64) * 40 + sc] = a1;
        *(int4*)&Bs[sr * 40 + sc] = b0;
        *(int4*)&Bs[(sr + 64) * 40 + sc] = b1;
        __syncthreads();
        GEMM_MFMA_STAGE();
    }

#pragma unroll
    for (int i = 0; i < 4; i++) {
#pragma unroll
        for (int j = 0; j < 4; j++) {
#pragma unroll
            for (int r = 0; r < 4; r++) {
                const int m = m0 + wm + i * 16 + fq * 4 + r;
                const int n = n0 + wn + j * 16 + fr;
                float v = acc[i][j][r];
                if (EPI == 0) {
                    ushort_t* C = (ushort_t*)Cv + (size_t)blockIdx.z * sCz;
                    C[(size_t)m * ldc + n] = f2bf(v * scale);
                } else if (EPI == 1) {
                    const float x = v + bias[n];
                    const float gl = 0.5f * x * (1.f + erff(x * 0.70710678118654752f));
                    ushort_t* C = (ushort_t*)Cv;
                    C[(size_t)m * ldc + n] = f2bf(gl);
                } else {
                    float* T = (float*)Cv;
                    const size_t idx = (size_t)m * ldc + n;
                    T[idx] = T[idx] + v + (init ? bias[n] : 0.f);
                }
            }
        }
    }
}

// Gate GEMM: A = concat(NX,CD) fp32 (convert in staging), B = WgT bf16 [512][1024]
// Epilogue: g = sigmoid(acc + bg); Fb = bf16(g*NX + (1-g)*CD).  M=BS,N=512,K=1024
__global__ __launch_bounds__(256) void gate_gemm(
    const float* __restrict__ NX, const float* __restrict__ CD,
    const ushort_t* __restrict__ WgT, const float* __restrict__ bg,
    ushort_t* __restrict__ Fb) {
    GEMM_PREAMBLE();
    const ushort_t* Bb = WgT + (size_t)n0 * 1024;

    for (int k0 = 0; k0 < 1024; k0 += 32) {
        const float* Asrc = (k0 < 512) ? NX : CD;
        const int kk = k0 & 511;
        const float* p0 = Asrc + (size_t)(m0 + sr) * 512 + kk + sc;
        const float* p1 = Asrc + (size_t)(m0 + sr + 64) * 512 + kk + sc;
        float4 f00 = *(const float4*)p0;       float4 f01 = *(const float4*)(p0 + 4);
        float4 f10 = *(const float4*)p1;       float4 f11 = *(const float4*)(p1 + 4);
        int4 b0 = *(const int4*)(Bb + (size_t)sr * 1024 + k0 + sc);
        int4 b1 = *(const int4*)(Bb + (size_t)(sr + 64) * 1024 + k0 + sc);
        short8 pa0 = pack8(f00, f01), pa1 = pack8(f10, f11);
        __syncthreads();
        *(short8*)&As[sr * 40 + sc] = pa0;
        *(short8*)&As[(sr + 64) * 40 + sc] = pa1;
        *(int4*)&Bs[sr * 40 + sc] = b0;
        *(int4*)&Bs[(sr + 64) * 40 + sc] = b1;
        __syncthreads();
        GEMM_MFMA_STAGE();
    }

#pragma unroll
    for (int i = 0; i < 4; i++) {
#pragma unroll
        for (int j = 0; j < 4; j++) {
#pragma unroll
            for (int r = 0; r < 4; r++) {
                const int m = m0 + wm + i * 16 + fq * 4 + r;
                const int n = n0 + wn + j * 16 + fr;
                const float z = acc[i][j][r] + bg[n];
                const float g = 1.f / (1.f + expf(-z));
                const size_t idx = (size_t)m * 512 + n;
                Fb[idx] = f2bf(g * NX[idx] + (1.f - g) * CD[idx]);
            }
        }
    }
}

// QK GEMM: Sc[z] = (Q[z] @ X[z]^T) * scale.  A = Fb bf16 [seq][512];
// Bt = X fp32 rows [seq][512] (natural layout IS [n][k]; convert in staging).
// M=N=2048, K=512.
__global__ __launch_bounds__(256) void qk_gemm(
    const ushort_t* __restrict__ Qb, const float* __restrict__ Xf,
    ushort_t* __restrict__ Sc) {
    GEMM_PREAMBLE();
    const ushort_t* Ab = Qb + (size_t)blockIdx.z * S * D + (size_t)m0 * D;
    const float*    Bf = Xf + (size_t)blockIdx.z * S * D + (size_t)n0 * D;
    ushort_t* Scb = Sc + (size_t)blockIdx.z * S * S;

    for (int k0 = 0; k0 < D; k0 += 32) {
        int4 a0 = *(const int4*)(Ab + (size_t)sr * D + k0 + sc);
        int4 a1 = *(const int4*)(Ab + (size_t)(sr + 64) * D + k0 + sc);
        const float* p0 = Bf + (size_t)sr * D + k0 + sc;
        const float* p1 = Bf + (size_t)(sr + 64) * D + k0 + sc;
        float4 f00 = *(const float4*)p0;       float4 f01 = *(const float4*)(p0 + 4);
        float4 f10 = *(const float4*)p1;       float4 f11 = *(const float4*)(p1 + 4);
        short8 pb0 = pack8(f00, f01), pb1 = pack8(f10, f11);
        __syncthreads();
        *(int4*)&As[sr * 40 + sc] = a0;
        *(int4*)&As[(sr + 64) * 40 + sc] = a1;
        *(short8*)&Bs[sr * 40 + sc] = pb0;
        *(short8*)&Bs[(sr + 64) * 40 + sc] = pb1;
        __syncthreads();
        GEMM_MFMA_STAGE();
    }

#pragma unroll
    for (int i = 0; i < 4; i++) {
#pragma unroll
        for (int j = 0; j < 4; j++) {
#pragma unroll
            for (int r = 0; r < 4; r++) {
                const int m = m0 + wm + i * 16 + fq * 4 + r;
                const int n = n0 + wn + j * 16 + fr;
                Scb[(size_t)m * S + n] = f2bf(acc[i][j][r] * ATTN_SCALE);
            }
        }
    }
}

// ---------------------------------------------------------------------------
// Softmax over bf16 rows of 2048, in place
// ---------------------------------------------------------------------------
__global__ __launch_bounds__(256) void softmax_bf16(ushort_t* __restrict__ Sc) {
    __shared__ float sm[4];
    ushort_t* row = Sc + (size_t)blockIdx.x * 2048;
    const int t = threadIdx.x;
    ushort_t raw[8];
    *(int4*)raw = *(const int4*)(row + t * 8);
    float e[8];
    float mx = -1e30f;
#pragma unroll
    for (int j = 0; j < 8; j++) { e[j] = bf2f(raw[j]); mx = fmaxf(mx, e[j]); }
    mx = blk_reduce_max(mx, sm);
    float s = 0.f;
#pragma unroll
    for (int j = 0; j < 8; j++) { e[j] = expf(e[j] - mx); s += e[j]; }
    s = blk_reduce_sum(s, sm);
    const float inv = 1.f / s;
#pragma unroll
    for (int j = 0; j < 8; j++) raw[j] = f2bf(e[j] * inv);
    *(int4*)(row + t * 8) = *(const int4*)raw;
}

// ---------------------------------------------------------------------------
// LN1: q = LN(fused + attn) -> qf (fp32, d_out) and qb (bf16)
// ---------------------------------------------------------------------------
__global__ __launch_bounds__(256) void ln1_kernel(
    const ushort_t* __restrict__ Fb, const ushort_t* __restrict__ Ab,
    const float* __restrict__ g1, const float* __restrict__ be1,
    float* __restrict__ qf, ushort_t* __restrict__ qb) {
    __shared__ float sm[4];
    const size_t base = (size_t)blockIdx.x * 512;
    const int t = threadIdx.x;
    const float v0 = bf2f(Fb[base + t]) + bf2f(Ab[base + t]);
    const float v1 = bf2f(Fb[base + t + 256]) + bf2f(Ab[base + t + 256]);
    const float mu = blk_reduce_sum(v0 + v1, sm) * (1.f / 512.f);
    const float d0 = v0 - mu, d1 = v1 - mu;
    const float var = blk_reduce_sum(d0 * d0 + d1 * d1, sm) * (1.f / 512.f);
    const float rs = rsqrtf(var + LN_EPS);
    const float y0 = d0 * rs * g1[t] + be1[t];
    const float y1 = d1 * rs * g1[t + 256] + be1[t + 256];
    qf[base + t] = y0;          qf[base + t + 256] = y1;
    qb[base + t] = f2bf(y0);    qb[base + t + 256] = f2bf(y1);
}

// Final LN in place on fp32
__global__ __launch_bounds__(256) void ln2_kernel(
    float* __restrict__ T, const float* __restrict__ g,
    const float* __restrict__ be) {
    __shared__ float sm[4];
    const size_t base = (size_t)blockIdx.x * 512;
    const int t = threadIdx.x;
    const float v0 = T[base + t];
    const float v1 = T[base + t + 256];
    const float mu = blk_reduce_sum(v0 + v1, sm) * (1.f / 512.f);
    const float d0 = v0 - mu, d1 = v1 - mu;
    const float var = blk_reduce_sum(d0 * d0 + d1 * d1, sm) * (1.f / 512.f);
    const float rs = rsqrtf(var + LN_EPS);
    T[base + t] = d0 * rs * g[t] + be[t];
    T[base + t + 256] = d1 * rs * g[t + 256] + be[t + 256];
}

// ---------------------------------------------------------------------------
extern "C" void kernel_launch(void* const* d_in, const int* in_sizes, int n_in,
                              void* d_out, int out_size, void* d_ws, size_t ws_size,
                              hipStream_t stream) {
    const float* NX  = (const float*)d_in[0];
    const float* X   = (const float*)d_in[1];
    const float* CD  = (const float*)d_in[2];
    const float* Wg  = (const float*)d_in[3];
    const float* bg  = (const float*)d_in[4];
    const float* W1  = (const float*)d_in[5];
    const float* b1  = (const float*)d_in[6];
    const float* W2  = (const float*)d_in[7];
    const float* b2  = (const float*)d_in[8];
    const float* g1  = (const float*)d_in[9];
    const float* be1 = (const float*)d_in[10];
    const float* g2  = (const float*)d_in[11];
    const float* be2 = (const float*)d_in[12];

    // ws layout (total exactly 50,331,648 B = proven-safe size):
    ushort_t* XbT = (ushort_t*)d_ws;                          // [8][512][2048] bf16
    ushort_t* Fb  = (ushort_t*)((char*)d_ws + 16777216);      // [BS][512] bf16
    ushort_t* R2  = (ushort_t*)((char*)d_ws + 33554432);      // 16.78 MB multi-use
    ushort_t* WgT = R2;                                       // [512][1024] (gate)
    ushort_t* attnb = R2;                                     // [BS][512] (attention)
    ushort_t* hbuf  = R2;                                     // [BS][512] (FFN half)
    ushort_t* qb  = XbT;                                      // after attention
    ushort_t* W1T = Fb;                                       // [1024][512] after LN1
    ushort_t* W2T = Fb + 524288;                              // [512][1024]
    ushort_t* Scb = (ushort_t*)d_out;                         // 4 batches [S][S] bf16
    float*    qf  = (float*)d_out;

    // 1) conversions: X^T per batch (for PV), Wg^T (for gate)
    transpose_cvt<<<dim3(512 / 32, 2048 / 32, 8), 256, 0, stream>>>(X, XbT, 2048, 512);
    transpose_cvt<<<dim3(512 / 32, 1024 / 32, 1), 256, 0, stream>>>(Wg, WgT, 1024, 512);

    // 2) gated fusion -> Fb (bf16)
    gate_gemm<<<dim3(4, 128), 256, 0, stream>>>(NX, CD, WgT, bg, Fb);

    // 3) attention in 2 groups of 4 batches; scores live in d_out as bf16
    for (int g = 0; g < 2; g++) {
        const size_t go = (size_t)g * 4 * S * 512;   // same elem offset in X, XbT, Fb
        qk_gemm<<<dim3(16, 16, 4), 256, 0, stream>>>(Fb + go, X + go, Scb);
        softmax_bf16<<<4 * S, 256, 0, stream>>>(Scb);
        gemm_std<0><<<dim3(4, 16, 4), 256, 0, stream>>>(
            Scb, S, (long)S * S,                // A = P [2048][2048]
            XbT + go, S, (long)D * S,           // Bt = X^T [512][2048]
            (void*)(attnb + go), 512, (long)S * 512, S, nullptr, 1.f, 0);
    }

    // 4) q = LN(fused + attn): qf -> d_out (scores dead), qb -> ws0 (XbT dead)
    ln1_kernel<<<BS, 256, 0, stream>>>(Fb, attnb, g1, be1, qf, qb);

    // 5) weight conversions into Fb region (Fb dead after LN1)
    transpose_cvt<<<dim3(1024 / 32, 512 / 32, 1), 256, 0, stream>>>(W1, W1T, 512, 1024);
    transpose_cvt<<<dim3(512 / 32, 1024 / 32, 1), 256, 0, stream>>>(W2, W2T, 1024, 512);

    // 6) FFN in 2 halves; h half in R2 (attnb dead); t accumulates in d_out
    for (int h = 0; h < 2; h++) {
        gemm_std<1><<<dim3(4, 128), 256, 0, stream>>>(
            qb, 512, 0, W1T + (size_t)h * 512 * 512, 512, 0,
            (void*)hbuf, 512, 0, 512, b1 + h * 512, 1.f, 0);
        gemm_std<2><<<dim3(4, 128), 256, 0, stream>>>(
            hbuf, 512, 0, W2T + h * 512, 1024, 0,
            (void*)qf, 512, 0, 512, b2, 1.f, h == 0 ? 1 : 0);
    }

    // 7) out = LN(t) in place in d_out
    ln2_kernel<<<BS, 256, 0, stream>>>(qf, g2, be2);
}

// Round 6
// 557.777 us; speedup vs baseline: 4.5233x; 1.0087x over previous
//
#include <hip/hip_runtime.h>
#include <math.h>

typedef unsigned short ushort_t;
typedef unsigned int uint_t;
typedef __attribute__((ext_vector_type(8))) short short8;
typedef __attribute__((ext_vector_type(4))) float floatx4;

// Problem dims
constexpr int B = 8;
constexpr int S = 2048;
constexpr int D = 512;
constexpr int BS = B * S;          // 16384 rows
constexpr float LN_EPS = 1e-5f;
constexpr float ATTN_SCALE = 0.04419417382415922f;  // 1/sqrt(512)

// R5 lesson (post-timing absmax 4.0, dur unchanged): global_load_lds staging
// on this toolchain gave 0 speedup and corrupted post-warm replays -> reverted
// to R4's proven padded-LDS VGPR staging. Also: do NOT alias Fb onto CDb/NXb —
// the gate epilogue of a fast n-block clobbers A-tiles still being staged by
// sibling n-blocks of the same m-range (cross-block race).

// ---------------------------------------------------------------------------
// bf16 helpers (RNE)
// ---------------------------------------------------------------------------
__device__ __forceinline__ ushort_t f2bf(float f) {
    union { float f; uint_t u; } x; x.f = f;
    uint_t r = x.u + 0x7fffu + ((x.u >> 16) & 1u);
    return (ushort_t)(r >> 16);
}
__device__ __forceinline__ float bf2f(ushort_t h) {
    union { uint_t u; float f; } y; y.u = ((uint_t)h) << 16;
    return y.f;
}
__device__ __forceinline__ short8 pack8(float4 a, float4 b) {
    short8 p;
    p[0] = (short)f2bf(a.x); p[1] = (short)f2bf(a.y);
    p[2] = (short)f2bf(a.z); p[3] = (short)f2bf(a.w);
    p[4] = (short)f2bf(b.x); p[5] = (short)f2bf(b.y);
    p[6] = (short)f2bf(b.z); p[7] = (short)f2bf(b.w);
    return p;
}

// ---------------------------------------------------------------------------
// Reductions (256-thread blocks = 4 waves of 64)
// ---------------------------------------------------------------------------
__device__ __forceinline__ float blk_reduce_sum(float v, float* sm) {
#pragma unroll
    for (int o = 32; o; o >>= 1) v += __shfl_down(v, o, 64);
    __syncthreads();
    if ((threadIdx.x & 63) == 0) sm[threadIdx.x >> 6] = v;
    __syncthreads();
    return sm[0] + sm[1] + sm[2] + sm[3];
}
__device__ __forceinline__ float blk_reduce_max(float v, float* sm) {
#pragma unroll
    for (int o = 32; o; o >>= 1) v = fmaxf(v, __shfl_down(v, o, 64));
    __syncthreads();
    if ((threadIdx.x & 63) == 0) sm[threadIdx.x >> 6] = v;
    __syncthreads();
    return fmaxf(fmaxf(sm[0], sm[1]), fmaxf(sm[2], sm[3]));
}

// ---------------------------------------------------------------------------
// fp32 [R][C] -> bf16 [C][R] transpose+convert; batched via blockIdx.z (z*R*C)
// ---------------------------------------------------------------------------
__global__ __launch_bounds__(256) void transpose_cvt(
    const float* __restrict__ in, ushort_t* __restrict__ out, int R, int C) {
    __shared__ float tl[32][33];
    const size_t zoff = (size_t)blockIdx.z * R * C;
    const int tx = threadIdx.x & 31, ty = threadIdx.x >> 5;  // ty 0..7
    const int c0 = blockIdx.x * 32, r0 = blockIdx.y * 32;
#pragma unroll
    for (int i = 0; i < 4; i++)
        tl[ty + i * 8][tx] = in[zoff + (size_t)(r0 + ty + i * 8) * C + c0 + tx];
    __syncthreads();
#pragma unroll
    for (int i = 0; i < 4; i++)
        out[zoff + (size_t)(c0 + ty + i * 8) * R + r0 + tx] = f2bf(tl[tx][ty + i * 8]);
}

// ---------------------------------------------------------------------------
// MFMA GEMM core A (128x128 tile) — used only by gate_gemm (HBM-heavy A reuse
// favors big tiles). Padded LDS stride 40 ushorts. Proven in R3/R4.
// ---------------------------------------------------------------------------
#define GEMM_PREAMBLE()                                                        \
    __shared__ ushort_t As[128 * 40];                                          \
    __shared__ ushort_t Bs[128 * 40];                                          \
    const int t = threadIdx.x;                                                 \
    const int m0 = blockIdx.y * 128, n0 = blockIdx.x * 128;                    \
    const int sr = t >> 2;               /* 0..63 */                           \
    const int sc = (t & 3) * 8;          /* 0,8,16,24 */                       \
    const int lane = t & 63, w = t >> 6;                                       \
    const int wm = (w >> 1) * 64, wn = (w & 1) * 64;                           \
    const int fr = lane & 15, fq = lane >> 4;                                  \
    floatx4 acc[4][4];                                                         \
    _Pragma("unroll") for (int i = 0; i < 4; i++)                              \
        _Pragma("unroll") for (int j = 0; j < 4; j++) {                        \
            acc[i][j][0] = 0.f; acc[i][j][1] = 0.f;                            \
            acc[i][j][2] = 0.f; acc[i][j][3] = 0.f; }

#define GEMM_MFMA_STAGE()                                                      \
    short8 af[4], bfg[4];                                                      \
    _Pragma("unroll") for (int i = 0; i < 4; i++) {                            \
        af[i]  = *(const short8*)&As[(wm + i * 16 + fr) * 40 + fq * 8];        \
        bfg[i] = *(const short8*)&Bs[(wn + i * 16 + fr) * 40 + fq * 8];        \
    }                                                                          \
    _Pragma("unroll") for (int i = 0; i < 4; i++)                              \
        _Pragma("unroll") for (int j = 0; j < 4; j++)                          \
            acc[i][j] = __builtin_amdgcn_mfma_f32_16x16x32_bf16(               \
                af[i], bfg[j], acc[i][j], 0, 0, 0);

// Gate GEMM: A = concat(NX,CD) fp32 (convert in staging), B = WgT bf16 [512][1024]
// Epilogue: g = sigmoid(acc + bg); Fb = bf16(g*NX + (1-g)*CD).  M=BS,N=512,K=1024
__global__ __launch_bounds__(256) void gate_gemm(
    const float* __restrict__ NX, const float* __restrict__ CD,
    const ushort_t* __restrict__ WgT, const float* __restrict__ bg,
    ushort_t* __restrict__ Fb) {
    GEMM_PREAMBLE();
    const ushort_t* Bb = WgT + (size_t)n0 * 1024;

    for (int k0 = 0; k0 < 1024; k0 += 32) {
        const float* Asrc = (k0 < 512) ? NX : CD;
        const int kk = k0 & 511;
        const float* p0 = Asrc + (size_t)(m0 + sr) * 512 + kk + sc;
        const float* p1 = Asrc + (size_t)(m0 + sr + 64) * 512 + kk + sc;
        float4 f00 = *(const float4*)p0;       float4 f01 = *(const float4*)(p0 + 4);
        float4 f10 = *(const float4*)p1;       float4 f11 = *(const float4*)(p1 + 4);
        int4 b0 = *(const int4*)(Bb + (size_t)sr * 1024 + k0 + sc);
        int4 b1 = *(const int4*)(Bb + (size_t)(sr + 64) * 1024 + k0 + sc);
        short8 pa0 = pack8(f00, f01), pa1 = pack8(f10, f11);
        __syncthreads();
        *(short8*)&As[sr * 40 + sc] = pa0;
        *(short8*)&As[(sr + 64) * 40 + sc] = pa1;
        *(int4*)&Bs[sr * 40 + sc] = b0;
        *(int4*)&Bs[(sr + 64) * 40 + sc] = b1;
        __syncthreads();
        GEMM_MFMA_STAGE();
    }

#pragma unroll
    for (int i = 0; i < 4; i++) {
#pragma unroll
        for (int j = 0; j < 4; j++) {
#pragma unroll
            for (int r = 0; r < 4; r++) {
                const int m = m0 + wm + i * 16 + fq * 4 + r;
                const int n = n0 + wn + j * 16 + fr;
                const float z = acc[i][j][r] + bg[n];
                const float g = 1.f / (1.f + expf(-z));
                const size_t idx = (size_t)m * 512 + n;
                Fb[idx] = f2bf(g * NX[idx] + (1.f - g) * CD[idx]);
            }
        }
    }
}

// ---------------------------------------------------------------------------
// MFMA GEMM core B (128x64 tile) — higher grid occupancy for the grid-starved
// qk/pv/ffn GEMMs (R4: pv Occupancy 11%, 1 block/CU). 4 waves stacked on M
// (wave tile 32x64), 8 MFMA/stage, LDS 15,360 B, acc 32 VGPR.
// ---------------------------------------------------------------------------
#define GEMM3_PREAMBLE()                                                       \
    __shared__ ushort_t As[128 * 40];                                          \
    __shared__ ushort_t Bs[64 * 40];                                           \
    const int t = threadIdx.x;                                                 \
    const int m0 = blockIdx.y * 128, n0 = blockIdx.x * 64;                     \
    const int sr = t >> 2;               /* 0..63 */                           \
    const int sc = (t & 3) * 8;          /* 0,8,16,24 */                       \
    const int lane = t & 63, w = t >> 6;                                       \
    const int wm = w * 32;                                                     \
    const int fr = lane & 15, fq = lane >> 4;                                  \
    floatx4 acc[2][4];                                                         \
    _Pragma("unroll") for (int i = 0; i < 2; i++)                              \
        _Pragma("unroll") for (int j = 0; j < 4; j++) {                        \
            acc[i][j][0] = 0.f; acc[i][j][1] = 0.f;                            \
            acc[i][j][2] = 0.f; acc[i][j][3] = 0.f; }

#define GEMM3_MFMA_STAGE()                                                     \
    short8 af[2], bfg[4];                                                      \
    _Pragma("unroll") for (int i = 0; i < 2; i++)                              \
        af[i]  = *(const short8*)&As[(wm + i * 16 + fr) * 40 + fq * 8];        \
    _Pragma("unroll") for (int j = 0; j < 4; j++)                              \
        bfg[j] = *(const short8*)&Bs[(j * 16 + fr) * 40 + fq * 8];             \
    _Pragma("unroll") for (int i = 0; i < 2; i++)                              \
        _Pragma("unroll") for (int j = 0; j < 4; j++)                          \
            acc[i][j] = __builtin_amdgcn_mfma_f32_16x16x32_bf16(               \
                af[i], bfg[j], acc[i][j], 0, 0, 0);

// EPI: 0 = scale + bf16 store; 1 = +bias, exact gelu, bf16 store;
//      2 = fp32 accumulate in place (T += acc [+ bias if init])
template <int EPI>
__global__ __launch_bounds__(256) void gemm3_std(
    const ushort_t* __restrict__ A, int lda, long sAz,
    const ushort_t* __restrict__ Bt, int ldb, long sBz,
    void* __restrict__ Cv, int ldc, long sCz,
    int K, const float* __restrict__ bias, float scale, int init) {
    GEMM3_PREAMBLE();
    const ushort_t* Ab = A + (size_t)blockIdx.z * sAz + (size_t)m0 * lda;
    const ushort_t* Bb = Bt + (size_t)blockIdx.z * sBz + (size_t)n0 * ldb;

    for (int k0 = 0; k0 < K; k0 += 32) {
        int4 a0 = *(const int4*)(Ab + (size_t)sr * lda + k0 + sc);
        int4 a1 = *(const int4*)(Ab + (size_t)(sr + 64) * lda + k0 + sc);
        int4 b0 = *(const int4*)(Bb + (size_t)sr * ldb + k0 + sc);
        __syncthreads();
        *(int4*)&As[sr * 40 + sc] = a0;
        *(int4*)&As[(sr + 64) * 40 + sc] = a1;
        *(int4*)&Bs[sr * 40 + sc] = b0;
        __syncthreads();
        GEMM3_MFMA_STAGE();
    }

#pragma unroll
    for (int i = 0; i < 2; i++) {
#pragma unroll
        for (int j = 0; j < 4; j++) {
#pragma unroll
            for (int r = 0; r < 4; r++) {
                const int m = m0 + wm + i * 16 + fq * 4 + r;
                const int n = n0 + j * 16 + fr;
                float v = acc[i][j][r];
                if (EPI == 0) {
                    ushort_t* C = (ushort_t*)Cv + (size_t)blockIdx.z * sCz;
                    C[(size_t)m * ldc + n] = f2bf(v * scale);
                } else if (EPI == 1) {
                    const float x = v + bias[n];
                    const float gl = 0.5f * x * (1.f + erff(x * 0.70710678118654752f));
                    ushort_t* C = (ushort_t*)Cv;
                    C[(size_t)m * ldc + n] = f2bf(gl);
                } else {
                    float* T = (float*)Cv;
                    const size_t idx = (size_t)m * ldc + n;
                    T[idx] = T[idx] + v + (init ? bias[n] : 0.f);
                }
            }
        }
    }
}

// QK GEMM (BN=64): Sc[z] = (Q[z] @ X[z]^T) * scale.  A = Fb bf16 [seq][512];
// B = X fp32 rows [seq][512] ([n][k] natural), converted in staging.
__global__ __launch_bounds__(256) void qk_gemm3(
    const ushort_t* __restrict__ Qb, const float* __restrict__ Xf,
    ushort_t* __restrict__ Sc) {
    GEMM3_PREAMBLE();
    const ushort_t* Ab = Qb + (size_t)blockIdx.z * S * D + (size_t)m0 * D;
    const float*    Bf = Xf + (size_t)blockIdx.z * S * D + (size_t)n0 * D;
    ushort_t* Scb = Sc + (size_t)blockIdx.z * S * S;

    for (int k0 = 0; k0 < D; k0 += 32) {
        int4 a0 = *(const int4*)(Ab + (size_t)sr * D + k0 + sc);
        int4 a1 = *(const int4*)(Ab + (size_t)(sr + 64) * D + k0 + sc);
        const float* p0 = Bf + (size_t)sr * D + k0 + sc;
        float4 f00 = *(const float4*)p0;       float4 f01 = *(const float4*)(p0 + 4);
        short8 pb0 = pack8(f00, f01);
        __syncthreads();
        *(int4*)&As[sr * 40 + sc] = a0;
        *(int4*)&As[(sr + 64) * 40 + sc] = a1;
        *(short8*)&Bs[sr * 40 + sc] = pb0;
        __syncthreads();
        GEMM3_MFMA_STAGE();
    }

#pragma unroll
    for (int i = 0; i < 2; i++) {
#pragma unroll
        for (int j = 0; j < 4; j++) {
#pragma unroll
            for (int r = 0; r < 4; r++) {
                const int m = m0 + wm + i * 16 + fq * 4 + r;
                const int n = n0 + j * 16 + fr;
                Scb[(size_t)m * S + n] = f2bf(acc[i][j][r] * ATTN_SCALE);
            }
        }
    }
}

// ---------------------------------------------------------------------------
// Softmax over bf16 rows of 2048, in place
// ---------------------------------------------------------------------------
__global__ __launch_bounds__(256) void softmax_bf16(ushort_t* __restrict__ Sc) {
    __shared__ float sm[4];
    ushort_t* row = Sc + (size_t)blockIdx.x * 2048;
    const int t = threadIdx.x;
    ushort_t raw[8];
    *(int4*)raw = *(const int4*)(row + t * 8);
    float e[8];
    float mx = -1e30f;
#pragma unroll
    for (int j = 0; j < 8; j++) { e[j] = bf2f(raw[j]); mx = fmaxf(mx, e[j]); }
    mx = blk_reduce_max(mx, sm);
    float s = 0.f;
#pragma unroll
    for (int j = 0; j < 8; j++) { e[j] = expf(e[j] - mx); s += e[j]; }
    s = blk_reduce_sum(s, sm);
    const float inv = 1.f / s;
#pragma unroll
    for (int j = 0; j < 8; j++) raw[j] = f2bf(e[j] * inv);
    *(int4*)(row + t * 8) = *(const int4*)raw;
}

// ---------------------------------------------------------------------------
// LN1: q = LN(fused + attn) -> qf (fp32) and qb (bf16)
// ---------------------------------------------------------------------------
__global__ __launch_bounds__(256) void ln1_kernel(
    const ushort_t* __restrict__ Fb, const ushort_t* __restrict__ Ab,
    const float* __restrict__ g1, const float* __restrict__ be1,
    float* __restrict__ qf, ushort_t* __restrict__ qb) {
    __shared__ float sm[4];
    const size_t base = (size_t)blockIdx.x * 512;
    const int t = threadIdx.x;
    const float v0 = bf2f(Fb[base + t]) + bf2f(Ab[base + t]);
    const float v1 = bf2f(Fb[base + t + 256]) + bf2f(Ab[base + t + 256]);
    const float mu = blk_reduce_sum(v0 + v1, sm) * (1.f / 512.f);
    const float d0 = v0 - mu, d1 = v1 - mu;
    const float var = blk_reduce_sum(d0 * d0 + d1 * d1, sm) * (1.f / 512.f);
    const float rs = rsqrtf(var + LN_EPS);
    const float y0 = d0 * rs * g1[t] + be1[t];
    const float y1 = d1 * rs * g1[t + 256] + be1[t + 256];
    qf[base + t] = y0;          qf[base + t + 256] = y1;
    qb[base + t] = f2bf(y0);    qb[base + t + 256] = f2bf(y1);
}

// Final LN in place on fp32
__global__ __launch_bounds__(256) void ln2_kernel(
    float* __restrict__ T, const float* __restrict__ g,
    const float* __restrict__ be) {
    __shared__ float sm[4];
    const size_t base = (size_t)blockIdx.x * 512;
    const int t = threadIdx.x;
    const float v0 = T[base + t];
    const float v1 = T[base + t + 256];
    const float mu = blk_reduce_sum(v0 + v1, sm) * (1.f / 512.f);
    const float d0 = v0 - mu, d1 = v1 - mu;
    const float var = blk_reduce_sum(d0 * d0 + d1 * d1, sm) * (1.f / 512.f);
    const float rs = rsqrtf(var + LN_EPS);
    T[base + t] = d0 * rs * g[t] + be[t];
    T[base + t + 256] = d1 * rs * g[t + 256] + be[t + 256];
}

// ---------------------------------------------------------------------------
extern "C" void kernel_launch(void* const* d_in, const int* in_sizes, int n_in,
                              void* d_out, int out_size, void* d_ws, size_t ws_size,
                              hipStream_t stream) {
    const float* NX  = (const float*)d_in[0];
    const float* X   = (const float*)d_in[1];
    const float* CD  = (const float*)d_in[2];
    const float* Wg  = (const float*)d_in[3];
    const float* bg  = (const float*)d_in[4];
    const float* W1  = (const float*)d_in[5];
    const float* b1  = (const float*)d_in[6];
    const float* W2  = (const float*)d_in[7];
    const float* b2  = (const float*)d_in[8];
    const float* g1  = (const float*)d_in[9];
    const float* be1 = (const float*)d_in[10];
    const float* g2  = (const float*)d_in[11];
    const float* be2 = (const float*)d_in[12];

    // ws: 3 slots x 16,777,216 B = 50,331,648 B (proven-safe since R2)
    // slot0: attnb -> hbuf;  slot1: Fb -> W1T/W2T;  slot2: WgT -> XbT -> qb
    // d_out: scores (bf16) -> qf (fp32, final)
    ushort_t* slot0 = (ushort_t*)d_ws;
    ushort_t* slot1 = (ushort_t*)((char*)d_ws + 16777216);
    ushort_t* slot2 = (ushort_t*)((char*)d_ws + 33554432);
    ushort_t* attnb = slot0;
    ushort_t* hbuf  = slot0;
    ushort_t* Fb    = slot1;
    ushort_t* W1T   = slot1;                    // [1024][512] bf16, 1 MB
    ushort_t* W2T   = slot1 + 524288;           // [512][1024] bf16, 1 MB
    ushort_t* WgT   = slot2;                    // [512][1024] bf16, 1 MB
    ushort_t* XbT   = slot2;                    // [8][512][2048] bf16, 16.78 MB
    ushort_t* qb    = slot2;                    // [BS][512] bf16
    ushort_t* Scb   = (ushort_t*)d_out;         // 4 batches [S][S] bf16
    float*    qf    = (float*)d_out;

    // 1) Wg^T (slot2)
    transpose_cvt<<<dim3(512 / 32, 1024 / 32, 1), 256, 0, stream>>>(Wg, WgT, 1024, 512);

    // 2) gated fusion -> Fb (128x128 core; fp32 A converted in staging)
    gate_gemm<<<dim3(4, 128), 256, 0, stream>>>(NX, CD, WgT, bg, Fb);

    // 3) X^T per batch into slot2 (WgT dead) — needed by PV
    transpose_cvt<<<dim3(512 / 32, 2048 / 32, 8), 256, 0, stream>>>(X, XbT, 2048, 512);

    // 4) attention in 2 groups of 4 batches; scores in d_out
    for (int g = 0; g < 2; g++) {
        const size_t go = (size_t)g * 4 * S * 512;
        qk_gemm3<<<dim3(32, 16, 4), 256, 0, stream>>>(Fb + go, X + go, Scb);
        softmax_bf16<<<4 * S, 256, 0, stream>>>(Scb);
        gemm3_std<0><<<dim3(8, 16, 4), 256, 0, stream>>>(
            Scb, S, (long)S * S,                // A = P [2048][2048]
            XbT + go, S, (long)D * S,           // Bt = X^T [512][2048]
            (void*)(attnb + go), 512, (long)S * 512, S, nullptr, 1.f, 0);
    }

    // 5) q = LN(fused + attn): qf -> d_out (scores dead), qb -> slot2 (XbT dead)
    ln1_kernel<<<BS, 256, 0, stream>>>(Fb, attnb, g1, be1, qf, qb);

    // 6) weight transposes into slot1 (Fb dead after LN1)
    transpose_cvt<<<dim3(1024 / 32, 512 / 32, 1), 256, 0, stream>>>(W1, W1T, 512, 1024);
    transpose_cvt<<<dim3(512 / 32, 1024 / 32, 1), 256, 0, stream>>>(W2, W2T, 1024, 512);

    // 7) FFN in 2 halves; hidden half in slot0 (attnb dead); t accumulates in d_out
    for (int h = 0; h < 2; h++) {
        gemm3_std<1><<<dim3(8, 128), 256, 0, stream>>>(
            qb, 512, 0, W1T + (size_t)h * 512 * 512, 512, 0,
            (void*)hbuf, 512, 0, 512, b1 + h * 512, 1.f, 0);
        gemm3_std<2><<<dim3(8, 128), 256, 0, stream>>>(
            hbuf, 512, 0, W2T + h * 512, 1024, 0,
            (void*)qf, 512, 0, 512, b2, 1.f, h == 0 ? 1 : 0);
    }

    // 8) out = LN(t) in place in d_out
    ln2_kernel<<<BS, 256, 0, stream>>>(qf, g2, be2);
}